// Round 3
// baseline (83.371 us; speedup 1.0000x reference)
//
#include <hip/hip_runtime.h>
#include <math.h>

#define SLEN 53
#define NPIX 2809
#define NPARAM 12
#define BLK 256
#define NSLOT 11        // zero-fill path: ceil(2809/256)

typedef float v2f __attribute__((ext_vector_type(2)));

__device__ __forceinline__ v2f sp(float c) { v2f r; r.x = c; r.y = c; return r; }
__device__ __forceinline__ v2f vfma(v2f a, v2f b, v2f c) {
    return __builtin_elementwise_fma(a, b, c);
}

// atan, full range, pair version: reciprocal reduction to [0,1] + 6-term
// minimax poly in x^2. Poly is pure fma -> v_pk_fma_f32 candidates.
__device__ __forceinline__ v2f fast_atan2v(v2f u) {
    v2f t = __builtin_elementwise_abs(u);
    float r0 = __builtin_amdgcn_rcpf(t.x);
    float r1 = __builtin_amdgcn_rcpf(t.y);
    v2f w;
    w.x = t.x > 1.0f ? r0 : t.x;
    w.y = t.y > 1.0f ? r1 : t.y;
    v2f z = w * w;
    v2f p = sp(-0.01172120f);
    p = vfma(p, z, sp( 0.05265332f));
    p = vfma(p, z, sp(-0.11643287f));
    p = vfma(p, z, sp( 0.19354346f));
    p = vfma(p, z, sp(-0.33262347f));
    p = vfma(p, z, sp( 0.99997726f));
    v2f r = w * p;
    r.x = t.x > 1.0f ? 1.57079632679489662f - r.x : r.x;
    r.y = t.y > 1.0f ? 1.57079632679489662f - r.y : r.y;
    return __builtin_elementwise_copysign(r, u);
}

// atanh(v) = 0.5*ln2*log2((1+v)*rcp(1-v)); |v| <= sqrt(1-q^2) <= 0.995.
__device__ __forceinline__ v2f fast_atanh2v(v2f v) {
    v2f a = __builtin_elementwise_abs(v);
    v2f num = a + 1.0f;
    v2f den = 1.0f - a;
    v2f rd; rd.x = __builtin_amdgcn_rcpf(den.x); rd.y = __builtin_amdgcn_rcpf(den.y);
    v2f t = num * rd;
    v2f lg; lg.x = __builtin_amdgcn_logf(t.x); lg.y = __builtin_amdgcn_logf(t.y);
    v2f r = 0.34657359027997264f * lg;
    return __builtin_elementwise_copysign(r, v);
}

// One pair of adjacent pixels (pb, pb+1), pb even. Heavy math in v2f so the
// backend can fuse independent fma/mul/add pairs into VOP3P v_pk_* ops.
__device__ __forceinline__ v2f pair_pixels(
    int pb, const float* __restrict__ Etab,
    float cosp, float sinp, float q, float qinv,
    float safe, float bos, float b, float cx, float cy, bool mb)
{
    const unsigned i0 = ((unsigned)pb * 39569u) >> 21;   // pb/53 exact (pb<4096)
    const int j0 = pb - (int)i0 * 53;
    const int wr = (j0 == 52);                           // elem1 wraps to next row
    const float jf0 = (float)j0, if0 = (float)i0;
    v2f jf;  jf.x = jf0;  jf.y = wr ? 0.0f : jf0 + 1.0f;
    v2f iff; iff.x = if0; iff.y = if0 + (float)wr;
    const float KC = 1.019230769230769231f;              // 53/52
    v2f xc = vfma(jf, sp(KC), sp(-27.0f));
    v2f yc = vfma(iff, sp(KC), sp(-27.0f));

    // ---- SIE deflection ----
    v2f dx = xc - cx;
    v2f dy = yc - cy;
    v2f xsie = vfma(dx, sp(cosp), dy * sinp);
    v2f ysie = vfma(dy, sp(cosp), (-dx) * sinp);
    v2f arg  = vfma(q * xsie, xsie, vfma(qinv * ysie, ysie, sp(1e-12f)));
    v2f rr; rr.x = __builtin_amdgcn_rsqf(arg.x); rr.y = __builtin_amdgcn_rsqf(arg.y);
    v2f xtg, ytg;
    if (mb) {                                            // block-uniform branch
        v2f srr = safe * rr;
        xtg = bos * fast_atan2v(srr * xsie);
        ytg = bos * fast_atanh2v(srr * ysie);
    } else {
        v2f brr = b * rr;
        xtg = brr * xsie;
        ytg = brr * ysie;
    }
    v2f xg = vfma(xtg, sp(cosp), -(ytg * sinp));
    v2f yg = vfma(ytg, sp(cosp),  xtg * sinp);

    // ---- bilinear sample coords ----
    v2f xs = (xc + 26.0f) - xg;
    v2f ys = (yc + 26.0f) - yg;
    v2f fx = __builtin_elementwise_floor(xs);
    v2f fy = __builtin_elementwise_floor(ys);
    v2f x0f = __builtin_elementwise_min(__builtin_elementwise_max(fx,        sp(0.0f)), sp(52.0f));
    v2f x1f = __builtin_elementwise_min(__builtin_elementwise_max(fx + 1.0f, sp(0.0f)), sp(52.0f));
    v2f y0f = __builtin_elementwise_min(__builtin_elementwise_max(fy,        sp(0.0f)), sp(52.0f));
    v2f y1f = __builtin_elementwise_min(__builtin_elementwise_max(fy + 1.0f, sp(0.0f)), sp(52.0f));

    // ---- corner Gaussian values from the per-tile LDS table ----
    v2f Ex0; Ex0.x = Etab[(int)x0f.x]; Ex0.y = Etab[(int)x0f.y];
    v2f Ex1; Ex1.x = Etab[(int)x1f.x]; Ex1.y = Etab[(int)x1f.y];
    v2f Ey0; Ey0.x = Etab[(int)y0f.x]; Ey0.y = Etab[(int)y0f.y];
    v2f Ey1; Ey1.x = Etab[(int)y1f.x]; Ey1.y = Etab[(int)y1f.y];

    // separable bilinear; sqrt(A*bl) folded into table -> no final scale
    v2f Fx = vfma(x1f - xs, Ex0, (xs - x0f) * Ex1);
    v2f Fy = vfma(y1f - ys, Ey0, (ys - y0f) * Ey1);
    return Fx * Fy;
}

__global__ __launch_bounds__(BLK) void lgtd_kernel(
    const float* __restrict__ lens_params,
    const float* __restrict__ bools,
    float* __restrict__ out)
{
    __shared__ float Etab[SLEN];
    const int tile = blockIdx.x;
    float* outp = out + (size_t)tile * NPIX;
    const int tid = threadIdx.x;

    const float bl = bools[tile];              // block-uniform
    if (bl == 0.0f) {                          // ~30% of tiles: pure zero-fill
        #pragma unroll
        for (int s = 0; s < NSLOT; ++s) {
            const int idx = s * BLK + tid;
            if (s < NSLOT - 1 || idx < NPIX) outp[idx] = 0.0f;
        }
        return;                                // whole block exits before barrier
    }

    const float* p = lens_params + tile * NPARAM;   // uniform -> s_load
    // ---- per-tile params, all fast intrinsics (block-uniform values) ----
    const float flux = __builtin_fmaf(p[0], 1000.0f, 100.0f);
    const float sg   = __builtin_fmaf(p[3], 3.0f, 1.0f);
    const float s2   = sg * sg;
    const float rs2  = __builtin_amdgcn_rcpf(s2);
    const float A    = flux * 0.15915494309189533577f * rs2;  // flux/(2*pi*s2)
    const float nh2  = -0.72134752044448170368f * rs2;        // -0.5*log2(e)/s2
    const float b  = p[7], cx = p[8], cy = p[9], e1 = p[10], e2 = p[11];
    const float rell = __builtin_amdgcn_rsqf(__builtin_fmaf(e1, e1, e2 * e2));
    const float cosp = e1 * rell;              // cos(atan(e2/e1)), e1>0
    const float sinp = e2 * rell;
    const float ell  = __builtin_fmaf(e1, cosp, e2 * sinp);   // = sqrt(e1^2+e2^2)
    const float q    = (1.0f - ell) * __builtin_amdgcn_rcpf(1.0f + ell);
    const float qinv = __builtin_amdgcn_rcpf(q);
    const float qf   = __builtin_amdgcn_sqrtf(qinv - q);
    const float safe = fmaxf(qf, 0.001f);
    const float bos  = b * __builtin_amdgcn_rcpf(safe);
    const bool  mb   = (qf >= 0.001f);         // always true for this data

    // ---- per-tile Gaussian corner table: E[k] = sqrt(A*bl)*exp2(nh2*(k-26)^2)
    const float sA = __builtin_amdgcn_sqrtf(A * bl);   // bl == 1 here
    if (tid < SLEN) {
        const float d = (float)tid - 26.0f;
        Etab[tid] = sA * __builtin_amdgcn_exp2f((nh2 * d) * d);
    }
    __syncthreads();

    // ---- 5 full pair-slots (base max 2558, pair always in-bounds) ----
    #pragma unroll
    for (int s = 0; s < 5; ++s) {
        const int base = s * (2 * BLK) + 2 * tid;   // even
        v2f r = pair_pixels(base, Etab, cosp, sinp, q, qinv, safe, bos, b, cx, cy, mb);
        __builtin_memcpy(outp + base, &r, 8);       // dwordx2 (4B-aligned ok)
    }
    // ---- tail slot: base 2560..3070 ----
    {
        const int base = 5 * (2 * BLK) + 2 * tid;
        if (base < 2808) {                          // even, <=2806: full pair
            v2f r = pair_pixels(base, Etab, cosp, sinp, q, qinv, safe, bos, b, cx, cy, mb);
            __builtin_memcpy(outp + base, &r, 8);
        } else if (base == 2808) {                  // single last pixel
            v2f r = pair_pixels(2808, Etab, cosp, sinp, q, qinv, safe, bos, b, cx, cy, mb);
            outp[2808] = r.x;
        }
    }
}

extern "C" void kernel_launch(void* const* d_in, const int* in_sizes, int n_in,
                              void* d_out, int out_size, void* d_ws, size_t ws_size,
                              hipStream_t stream) {
    const float* lens  = (const float*)d_in[0];  // (N, 1, 12) fp32
    const float* bools = (const float*)d_in[1];  // (N, 1, 1)  fp32
    float* out = (float*)d_out;                  // (N, 1, 1, 53, 53) fp32
    const int n_tiles = in_sizes[1];
    lgtd_kernel<<<n_tiles, BLK, 0, stream>>>(lens, bools, out);
}